// Round 1
// baseline (420.210 us; speedup 1.0000x reference)
//
#include <hip/hip_runtime.h>
#include <hip/hip_bf16.h>
#include <math.h>

typedef __bf16 bf16x8 __attribute__((ext_vector_type(8)));
typedef __bf16 bf16x4 __attribute__((ext_vector_type(4)));
typedef __bf16 bf16x2 __attribute__((ext_vector_type(2)));
typedef float f32x4 __attribute__((ext_vector_type(4)));

#define B_SZ 32
#define T_SZ 2048
#define D_SZ 512
#define K_SZ 128
#define TC 16
#define NC 128   // T_SZ / TC

__device__ __forceinline__ float softplus_f(float x){
  return x > 20.f ? x : log1pf(expf(x));
}

// ---------------------------------------------------------------------------
// Kernel 1: spectral norm power iteration. Writes W_sn (pre-scaled by 1/sigma)
// in MFMA B-fragment order: frag i = (ks*8 + jj)*64 + lane holds
// W[jj*16 + (lane&15)][ks*32 + (lane>>4)*8 .. +8] as bf16x8, so the GEMM's
// W loads are fully coalesced 16B/lane.
// ---------------------------------------------------------------------------
__global__ __launch_bounds__(512) void sn_prep(const float* __restrict__ W,
                                               const float* __restrict__ u_sn,
                                               __bf16* __restrict__ Wb){
  __shared__ float red[512];
  __shared__ float vsh[512];
  __shared__ float ush[128];
  const int t = threadIdx.x;
  if (t < 128) ush[t] = u_sn[t];
  __syncthreads();
  // t1[d] = sum_k W[k,d] * u[k]   (coalesced over d)
  float t1 = 0.f;
  #pragma unroll 8
  for (int k = 0; k < K_SZ; ++k) t1 += W[k*D_SZ + t] * ush[k];
  red[t] = t1 * t1;
  __syncthreads();
  for (int s = 256; s > 0; s >>= 1){ if (t < s) red[t] += red[t+s]; __syncthreads(); }
  const float n1 = sqrtf(red[0]);
  vsh[t] = t1 / (n1 + 1e-6f);
  __syncthreads();
  // t2[k] = sum_d W[k,d] * v[d]  (float4 per row)
  float t2 = 0.f;
  if (t < 128){
    const float4* Wr = (const float4*)(W + (size_t)t * D_SZ);
    const float4* vp = (const float4*)vsh;
    #pragma unroll 8
    for (int d = 0; d < D_SZ/4; ++d){
      const float4 a = Wr[d], v = vp[d];
      t2 += a.x*v.x + a.y*v.y + a.z*v.z + a.w*v.w;
    }
  }
  __syncthreads();
  red[t] = (t < 128) ? t2*t2 : 0.f;
  __syncthreads();
  for (int s = 256; s > 0; s >>= 1){ if (t < s) red[t] += red[t+s]; __syncthreads(); }
  const float n2sq = red[0];
  const float sigma = n2sq / (sqrtf(n2sq) + 1e-6f);   // u1 . (W v)
  const float inv = 1.f / sigma;
  // emit in fragment order
  for (int i = t; i < (K_SZ*D_SZ)/8; i += 512){
    const int ls = i & 63, fr = i >> 6;
    const int jj = fr & 7,  ks = fr >> 3;
    const int n = jj*16 + (ls & 15);
    const int k = ks*32 + ((ls >> 4) << 3);
    const float4* src = (const float4*)(W + (size_t)n*D_SZ + k);
    const float4 s0 = src[0], s1 = src[1];
    bf16x8 o;
    o[0]=(__bf16)(s0.x*inv); o[1]=(__bf16)(s0.y*inv);
    o[2]=(__bf16)(s0.z*inv); o[3]=(__bf16)(s0.w*inv);
    o[4]=(__bf16)(s1.x*inv); o[5]=(__bf16)(s1.y*inv);
    o[6]=(__bf16)(s1.z*inv); o[7]=(__bf16)(s1.w*inv);
    ((bf16x8*)Wb)[i] = o;
  }
}

// ---------------------------------------------------------------------------
// Kernel 2: u = x @ W_sn^T   (M=65536, N=128, K=512), bf16 MFMA, bf16 out.
// LDS-free, barrier-free: each wave owns a disjoint 32-row x 128-col tile
// (acc[2][8]). A-fragments are loaded straight from global fp32 with a
// depth-2 register prefetch (per-wave ~8KB in flight -> BW-saturating at
// 12 waves/CU); B-fragments come from the fragment-ordered Wb (L2-hot,
// 1KB fully-coalesced loads). MFMA k-order identical to previous version.
// ---------------------------------------------------------------------------
__global__ __launch_bounds__(256, 3) void gemm_xw(const float* __restrict__ X,
                                                  const __bf16* __restrict__ Wf,
                                                  __bf16* __restrict__ U){
  const int tid = threadIdx.x;
  const int lane = tid & 63;
  const int wid  = tid >> 6;                       // 0..3 -> 32-row slice
  const int rowbase = blockIdx.x*128 + wid*32;
  const int r16 = lane & 15, kq = lane >> 4;
  const float* X0 = X + (size_t)(rowbase + r16)*D_SZ + (kq << 3);
  const float* X1 = X0 + (size_t)16*D_SZ;
  const bf16x8* Wp = (const bf16x8*)Wf + lane;     // + (ks*8+jj)*64
  f32x4 acc[2][8] = {};

  float4 pa[2][4];
  #pragma unroll
  for (int p = 0; p < 2; ++p){
    const float4* q0 = (const float4*)(X0 + p*32);
    const float4* q1 = (const float4*)(X1 + p*32);
    pa[p][0]=q0[0]; pa[p][1]=q0[1]; pa[p][2]=q1[0]; pa[p][3]=q1[1];
  }
  #pragma unroll
  for (int ks = 0; ks < 16; ++ks){
    const int cur = ks & 1;
    bf16x8 a0, a1;
    {
      const float4 u0 = pa[cur][0], u1 = pa[cur][1];
      a0[0]=(__bf16)u0.x; a0[1]=(__bf16)u0.y; a0[2]=(__bf16)u0.z; a0[3]=(__bf16)u0.w;
      a0[4]=(__bf16)u1.x; a0[5]=(__bf16)u1.y; a0[6]=(__bf16)u1.z; a0[7]=(__bf16)u1.w;
      const float4 u2 = pa[cur][2], u3 = pa[cur][3];
      a1[0]=(__bf16)u2.x; a1[1]=(__bf16)u2.y; a1[2]=(__bf16)u2.z; a1[3]=(__bf16)u2.w;
      a1[4]=(__bf16)u3.x; a1[5]=(__bf16)u3.y; a1[6]=(__bf16)u3.z; a1[7]=(__bf16)u3.w;
    }
    if (ks + 2 < 16){
      const float4* q0 = (const float4*)(X0 + (ks+2)*32);
      const float4* q1 = (const float4*)(X1 + (ks+2)*32);
      pa[cur][0]=q0[0]; pa[cur][1]=q0[1]; pa[cur][2]=q1[0]; pa[cur][3]=q1[1];
    }
    #pragma unroll
    for (int jj = 0; jj < 8; ++jj){
      const bf16x8 bv = Wp[(ks*8 + jj)*64];
      acc[0][jj] = __builtin_amdgcn_mfma_f32_16x16x32_bf16(a0, bv, acc[0][jj], 0, 0, 0);
      acc[1][jj] = __builtin_amdgcn_mfma_f32_16x16x32_bf16(a1, bv, acc[1][jj], 0, 0, 0);
    }
  }
  // epilogue: C/D layout col = lane&15, row = (lane>>4)*4 + reg (m89-verified)
  #pragma unroll
  for (int ii = 0; ii < 2; ++ii){
    const int m0 = rowbase + ii*16 + (kq << 2);
    #pragma unroll
    for (int jj = 0; jj < 8; ++jj){
      const int n = jj*16 + r16;
      #pragma unroll
      for (int r = 0; r < 4; ++r)
        U[(size_t)(m0 + r)*K_SZ + n] = (__bf16)acc[ii][jj][r];
    }
  }
}

// ---------------------------------------------------------------------------
// Kernel 3 (pass A): per-chunk summaries. Thread = (chunk, 2 k-channels).
// Block = 256 threads = 4 chunks x 64 k-pairs. Grid = (NC/4, B) = 1024 blocks.
// ---------------------------------------------------------------------------
__global__ __launch_bounds__(256) void pass_a(
    const float* __restrict__ alpha_mod, const float* __restrict__ omega_mod,
    const __bf16* __restrict__ Uarr, const float* __restrict__ dt,
    const float* __restrict__ tau_mod, const float* __restrict__ s_real,
    const float* __restrict__ s_imag, const float* __restrict__ tau_raw,
    const float* __restrict__ bvec,
    float2* __restrict__ sumA, float2* __restrict__ sumT,
    float2* __restrict__ Zr, float2* __restrict__ Zi){
  const int t = threadIdx.x;
  const int kh = t & 63;        // k-pair index: k = kh*2, kh*2+1
  const int cl = t >> 6;        // chunk-local 0..3
  const int b = blockIdx.y;
  const int c = blockIdx.x*4 + cl;
  const int t0 = c * TC;
  __shared__ float sdt[4*TC], ssc[4*TC];
  if (t < 4*TC){
    const int tg = blockIdx.x*4*TC + t;
    sdt[t] = dt[b*T_SZ + tg];
    ssc[t] = __expf(tau_mod[b*T_SZ + tg]);
  }
  __syncthreads();
  const float tau = softplus_f(tau_raw[0]) + 1e-3f;
  const float2 sr = ((const float2*)s_real)[kh];
  const float2 si = ((const float2*)s_imag)[kh];
  const float2 bk = ((const float2*)bvec)[kh];
  const float a0[2] = {(softplus_f(sr.x)+1e-6f)*tau, (softplus_f(sr.y)+1e-6f)*tau};
  const float w0[2] = {si.x*tau, si.y*tau};
  float zr[2]={0,0}, zs[2]={0,0}, sA[2]={0,0}, sT[2]={0,0};
  const float* sd = sdt + cl*TC;
  const float* ss = ssc + cl*TC;
  const size_t row = (size_t)(b*T_SZ + t0);
  const float2* amp = (const float2*)(alpha_mod + row*K_SZ) + kh;
  const float2* omp = (const float2*)(omega_mod + row*K_SZ) + kh;
  const bf16x2* up  = (const bf16x2*)(Uarr + row*K_SZ) + kh;
  #pragma unroll 8
  for (int i = 0; i < TC; ++i){
    const float2 am = amp[(size_t)i*64];
    const float2 om = omp[(size_t)i*64];
    const bf16x2 u2 = up[(size_t)i*64];
    const float scdt = ss[i] * sd[i];
    #pragma unroll
    for (int j = 0; j < 2; ++j){
      const float ad = a0[j] * __expf(j ? am.y : am.x) * scdt;
      const float th = w0[j] * __expf(j ? om.y : om.x) * scdt;
      const float rho = __expf(-ad);
      float st, ct; __sincosf(th, &st, &ct);
      const float uu = (float)u2[j] + (j ? bk.y : bk.x);
      const float nr = rho*(zr[j]*ct - zs[j]*st) + uu;
      const float ns = rho*(zr[j]*st + zs[j]*ct);
      zr[j] = nr; zs[j] = ns;
      sA[j] += ad; sT[j] += th;
    }
  }
  const size_t idx = ((size_t)(b*NC + c))*64 + kh;
  sumA[idx] = make_float2(sA[0], sA[1]);
  sumT[idx] = make_float2(sT[0], sT[1]);
  Zr[idx]   = make_float2(zr[0], zr[1]);
  Zi[idx]   = make_float2(zs[0], zs[1]);
}

// ---------------------------------------------------------------------------
// Kernel 4 (pass B): scan chunk summaries. Block = one batch (64 threads =
// 64 k-pairs), grid = B. Exclusive prefix written to Cr/Ci.
// ---------------------------------------------------------------------------
__global__ __launch_bounds__(64) void pass_b(
    const float2* __restrict__ sumA, const float2* __restrict__ sumT,
    const float2* __restrict__ Zr, const float2* __restrict__ Zi,
    float2* __restrict__ Cr, float2* __restrict__ Ci){
  const int b = blockIdx.x, kh = threadIdx.x;
  float er[2]={0,0}, ei[2]={0,0};
  #pragma unroll 8
  for (int c = 0; c < NC; ++c){
    const size_t idx = ((size_t)(b*NC + c))*64 + kh;
    Cr[idx] = make_float2(er[0], er[1]);
    Ci[idx] = make_float2(ei[0], ei[1]);
    const float2 sa = sumA[idx], st4 = sumT[idx];
    const float2 zr = Zr[idx],   zi  = Zi[idx];
    #pragma unroll
    for (int j = 0; j < 2; ++j){
      const float rho = __expf(-(j ? sa.y : sa.x));
      float st, ct; __sincosf(j ? st4.y : st4.x, &st, &ct);
      const float ar = rho*ct, ai = rho*st;
      const float zrj = j ? zr.y : zr.x, zij = j ? zi.y : zi.x;
      const float nr = zrj + ar*er[j] - ai*ei[j];
      const float ni = zij + ar*ei[j] + ai*er[j];
      er[j] = nr; ei[j] = ni;
    }
  }
}

// ---------------------------------------------------------------------------
// Kernel 5 (pass C): replay chunks from carry-in, write [B,T,2K] output
// ---------------------------------------------------------------------------
__global__ __launch_bounds__(256) void pass_c(
    const float* __restrict__ alpha_mod, const float* __restrict__ omega_mod,
    const __bf16* __restrict__ Uarr, const float* __restrict__ dt,
    const float* __restrict__ tau_mod, const float* __restrict__ s_real,
    const float* __restrict__ s_imag, const float* __restrict__ tau_raw,
    const float* __restrict__ bvec,
    const float2* __restrict__ Cr, const float2* __restrict__ Ci,
    float* __restrict__ out){
  const int t = threadIdx.x;
  const int kh = t & 63;
  const int cl = t >> 6;
  const int b = blockIdx.y;
  const int c = blockIdx.x*4 + cl;
  const int t0 = c * TC;
  __shared__ float sdt[4*TC], ssc[4*TC];
  if (t < 4*TC){
    const int tg = blockIdx.x*4*TC + t;
    sdt[t] = dt[b*T_SZ + tg];
    ssc[t] = __expf(tau_mod[b*T_SZ + tg]);
  }
  __syncthreads();
  const float tau = softplus_f(tau_raw[0]) + 1e-3f;
  const float2 sr = ((const float2*)s_real)[kh];
  const float2 si = ((const float2*)s_imag)[kh];
  const float2 bk = ((const float2*)bvec)[kh];
  const float a0[2] = {(softplus_f(sr.x)+1e-6f)*tau, (softplus_f(sr.y)+1e-6f)*tau};
  const float w0[2] = {si.x*tau, si.y*tau};
  const size_t cidx = ((size_t)(b*NC + c))*64 + kh;
  const float2 cr = Cr[cidx], cim = Ci[cidx];
  float zr[2] = {cr.x, cr.y}, zs[2] = {cim.x, cim.y};
  const float* sd = sdt + cl*TC;
  const float* ss = ssc + cl*TC;
  const size_t row = (size_t)(b*T_SZ + t0);
  const float2* amp = (const float2*)(alpha_mod + row*K_SZ) + kh;
  const float2* omp = (const float2*)(omega_mod + row*K_SZ) + kh;
  const bf16x2* up  = (const bf16x2*)(Uarr + row*K_SZ) + kh;
  float2* outC = (float2*)(out + row*(2*K_SZ)) + kh;          // stride 128 float2 per t
  float2* outS = outC + 64;
  #pragma unroll 8
  for (int i = 0; i < TC; ++i){
    const float2 am = amp[(size_t)i*64];
    const float2 om = omp[(size_t)i*64];
    const bf16x2 u2 = up[(size_t)i*64];
    const float scdt = ss[i] * sd[i];
    #pragma unroll
    for (int j = 0; j < 2; ++j){
      const float ad = a0[j] * __expf(j ? am.y : am.x) * scdt;
      const float th = w0[j] * __expf(j ? om.y : om.x) * scdt;
      const float rho = __expf(-ad);
      float st, ct; __sincosf(th, &st, &ct);
      const float uu = (float)u2[j] + (j ? bk.y : bk.x);
      const float nr = rho*(zr[j]*ct - zs[j]*st) + uu;
      const float ns = rho*(zr[j]*st + zs[j]*ct);
      zr[j] = nr; zs[j] = ns;
    }
    outC[(size_t)i*128] = make_float2(zr[0], zr[1]);
    outS[(size_t)i*128] = make_float2(zs[0], zs[1]);
  }
}

// ---------------------------------------------------------------------------
extern "C" void kernel_launch(void* const* d_in, const int* in_sizes, int n_in,
                              void* d_out, int out_size, void* d_ws, size_t ws_size,
                              hipStream_t stream){
  (void)in_sizes; (void)n_in; (void)out_size; (void)ws_size;
  const float* x         = (const float*)d_in[0];
  const float* dt        = (const float*)d_in[1];
  const float* alpha_mod = (const float*)d_in[2];
  const float* omega_mod = (const float*)d_in[3];
  const float* tau_mod   = (const float*)d_in[4];
  const float* s_real    = (const float*)d_in[5];
  const float* s_imag    = (const float*)d_in[6];
  const float* tau_raw   = (const float*)d_in[7];
  const float* W         = (const float*)d_in[8];
  const float* bvec      = (const float*)d_in[9];
  const float* u_sn      = (const float*)d_in[10];
  float* out = (float*)d_out;

  char* w = (char*)d_ws;
  __bf16* Wb = (__bf16*)w;                                  // 128 KiB (frag-ordered)
  __bf16* U  = (__bf16*)(w + 131072);                       // 16 MiB (bf16 u)
  size_t off = 131072 + (size_t)B_SZ*T_SZ*K_SZ*2;
  const size_t SUMN = (size_t)B_SZ*NC*K_SZ*4;               // 2 MiB each
  float2* sumA = (float2*)(w + off); off += SUMN;
  float2* sumT = (float2*)(w + off); off += SUMN;
  float2* Zr   = (float2*)(w + off); off += SUMN;
  float2* Zi   = (float2*)(w + off); off += SUMN;
  float2* Cr   = (float2*)(w + off); off += SUMN;
  float2* Ci   = (float2*)(w + off); off += SUMN;

  sn_prep<<<1, 512, 0, stream>>>(W, u_sn, Wb);
  gemm_xw<<<(B_SZ*T_SZ)/128, 256, 0, stream>>>(x, Wb, U);
  pass_a<<<dim3(NC/4, B_SZ), 256, 0, stream>>>(alpha_mod, omega_mod, U, dt, tau_mod,
                                               s_real, s_imag, tau_raw, bvec,
                                               sumA, sumT, Zr, Zi);
  pass_b<<<B_SZ, 64, 0, stream>>>(sumA, sumT, Zr, Zi, Cr, Ci);
  pass_c<<<dim3(NC/4, B_SZ), 256, 0, stream>>>(alpha_mod, omega_mod, U, dt, tau_mod,
                                               s_real, s_imag, tau_raw, bvec,
                                               Cr, Ci, out);
}

// Round 2
// 355.979 us; speedup vs baseline: 1.1804x; 1.1804x over previous
//
#include <hip/hip_runtime.h>
#include <hip/hip_bf16.h>
#include <math.h>

typedef __bf16 bf16x8 __attribute__((ext_vector_type(8)));
typedef __bf16 bf16x4 __attribute__((ext_vector_type(4)));
typedef __bf16 bf16x2 __attribute__((ext_vector_type(2)));
typedef float f32x4 __attribute__((ext_vector_type(4)));

#define B_SZ 32
#define T_SZ 2048
#define D_SZ 512
#define K_SZ 128
#define TC 16
#define NC 128   // T_SZ / TC

__device__ __forceinline__ float softplus_f(float x){
  return x > 20.f ? x : log1pf(expf(x));
}

// ---------------------------------------------------------------------------
// Kernel 1: spectral norm power iteration. Writes W_sn (pre-scaled by 1/sigma)
// in MFMA B-fragment order: frag fr = ks*8 + jj, lane ls holds
// W[jj*16 + (ls&15)][ks*32 + (ls>>4)*8 .. +8] as bf16x8.
// Emit loop: coalesced row-major READS (wave covers one 2KB row), scattered
// 16B writes (one-time 128KB, write-combined).
// ---------------------------------------------------------------------------
__global__ __launch_bounds__(512) void sn_prep(const float* __restrict__ W,
                                               const float* __restrict__ u_sn,
                                               __bf16* __restrict__ Wb){
  __shared__ float red[512];
  __shared__ float vsh[512];
  __shared__ float ush[128];
  const int t = threadIdx.x;
  if (t < 128) ush[t] = u_sn[t];
  __syncthreads();
  // t1[d] = sum_k W[k,d] * u[k]   (coalesced over d)
  float t1 = 0.f;
  #pragma unroll 8
  for (int k = 0; k < K_SZ; ++k) t1 += W[k*D_SZ + t] * ush[k];
  red[t] = t1 * t1;
  __syncthreads();
  for (int s = 256; s > 0; s >>= 1){ if (t < s) red[t] += red[t+s]; __syncthreads(); }
  const float n1 = sqrtf(red[0]);
  vsh[t] = t1 / (n1 + 1e-6f);
  __syncthreads();
  // t2[k] = sum_d W[k,d] * v[d]  (float4 per row)
  float t2 = 0.f;
  if (t < 128){
    const float4* Wr = (const float4*)(W + (size_t)t * D_SZ);
    const float4* vp = (const float4*)vsh;
    #pragma unroll 8
    for (int d = 0; d < D_SZ/4; ++d){
      const float4 a = Wr[d], v = vp[d];
      t2 += a.x*v.x + a.y*v.y + a.z*v.z + a.w*v.w;
    }
  }
  __syncthreads();
  red[t] = (t < 128) ? t2*t2 : 0.f;
  __syncthreads();
  for (int s = 256; s > 0; s >>= 1){ if (t < s) red[t] += red[t+s]; __syncthreads(); }
  const float n2sq = red[0];
  const float sigma = n2sq / (sqrtf(n2sq) + 1e-6f);   // u1 . (W v)
  const float inv = 1.f / sigma;
  // coalesced read of W, scattered write into fragment order
  for (int i = t; i < (K_SZ*D_SZ)/8; i += 512){
    const int n = i >> 6;            // row (0..127)
    const int k = (i & 63) << 3;     // col start (0..504, step 8)
    const float4* src = (const float4*)(W + (size_t)n*D_SZ + k);
    const float4 s0 = src[0], s1 = src[1];
    bf16x8 o;
    o[0]=(__bf16)(s0.x*inv); o[1]=(__bf16)(s0.y*inv);
    o[2]=(__bf16)(s0.z*inv); o[3]=(__bf16)(s0.w*inv);
    o[4]=(__bf16)(s1.x*inv); o[5]=(__bf16)(s1.y*inv);
    o[6]=(__bf16)(s1.z*inv); o[7]=(__bf16)(s1.w*inv);
    const int fr = ((k >> 5) << 3) | (n >> 4);
    const int ls = (n & 15) | (((k >> 3) & 3) << 4);
    ((bf16x8*)Wb)[fr*64 + ls] = o;
  }
}

// ---------------------------------------------------------------------------
// Kernel 2: u = x @ W_sn^T   (M=65536, N=128, K=512), bf16 MFMA, bf16 out.
// LDS-free, barrier-free: each wave owns a disjoint 32-row x 128-col tile
// (acc[2][8]). A-fragments loaded straight from global fp32 with a depth-2
// register prefetch; B-fragments from fragment-ordered Wb (L1/L2-hot,
// fully-coalesced 1KB loads). MFMA k-order identical to previous version.
// ---------------------------------------------------------------------------
__global__ __launch_bounds__(256, 3) void gemm_xw(const float* __restrict__ X,
                                                  const __bf16* __restrict__ Wf,
                                                  __bf16* __restrict__ U){
  const int tid = threadIdx.x;
  const int lane = tid & 63;
  const int wid  = tid >> 6;                       // 0..3 -> 32-row slice
  const int rowbase = blockIdx.x*128 + wid*32;
  const int r16 = lane & 15, kq = lane >> 4;
  const float* X0 = X + (size_t)(rowbase + r16)*D_SZ + (kq << 3);
  const float* X1 = X0 + (size_t)16*D_SZ;
  const bf16x8* Wp = (const bf16x8*)Wf + lane;     // + (ks*8+jj)*64
  f32x4 acc[2][8] = {};

  float4 pa[2][4];
  #pragma unroll
  for (int p = 0; p < 2; ++p){
    const float4* q0 = (const float4*)(X0 + p*32);
    const float4* q1 = (const float4*)(X1 + p*32);
    pa[p][0]=q0[0]; pa[p][1]=q0[1]; pa[p][2]=q1[0]; pa[p][3]=q1[1];
  }
  #pragma unroll
  for (int ks = 0; ks < 16; ++ks){
    const int cur = ks & 1;
    bf16x8 a0, a1;
    {
      const float4 u0 = pa[cur][0], u1 = pa[cur][1];
      a0[0]=(__bf16)u0.x; a0[1]=(__bf16)u0.y; a0[2]=(__bf16)u0.z; a0[3]=(__bf16)u0.w;
      a0[4]=(__bf16)u1.x; a0[5]=(__bf16)u1.y; a0[6]=(__bf16)u1.z; a0[7]=(__bf16)u1.w;
      const float4 u2 = pa[cur][2], u3 = pa[cur][3];
      a1[0]=(__bf16)u2.x; a1[1]=(__bf16)u2.y; a1[2]=(__bf16)u2.z; a1[3]=(__bf16)u2.w;
      a1[4]=(__bf16)u3.x; a1[5]=(__bf16)u3.y; a1[6]=(__bf16)u3.z; a1[7]=(__bf16)u3.w;
    }
    if (ks + 2 < 16){
      const float4* q0 = (const float4*)(X0 + (ks+2)*32);
      const float4* q1 = (const float4*)(X1 + (ks+2)*32);
      pa[cur][0]=q0[0]; pa[cur][1]=q0[1]; pa[cur][2]=q1[0]; pa[cur][3]=q1[1];
    }
    #pragma unroll
    for (int jj = 0; jj < 8; ++jj){
      const bf16x8 bv = Wp[(ks*8 + jj)*64];
      acc[0][jj] = __builtin_amdgcn_mfma_f32_16x16x32_bf16(a0, bv, acc[0][jj], 0, 0, 0);
      acc[1][jj] = __builtin_amdgcn_mfma_f32_16x16x32_bf16(a1, bv, acc[1][jj], 0, 0, 0);
    }
  }
  // epilogue: C/D layout col = lane&15, row = (lane>>4)*4 + reg (m89-verified)
  #pragma unroll
  for (int ii = 0; ii < 2; ++ii){
    const int m0 = rowbase + ii*16 + (kq << 2);
    #pragma unroll
    for (int jj = 0; jj < 8; ++jj){
      const int n = jj*16 + r16;
      #pragma unroll
      for (int r = 0; r < 4; ++r)
        U[(size_t)(m0 + r)*K_SZ + n] = (__bf16)acc[ii][jj][r];
    }
  }
}

// ---------------------------------------------------------------------------
// Kernel 3 (pass A): per-chunk summaries. Thread = (chunk, 2 k-channels).
// Block = 256 threads = 4 chunks x 64 k-pairs. Grid = (NC/4, B) = 1024 blocks.
// ---------------------------------------------------------------------------
__global__ __launch_bounds__(256) void pass_a(
    const float* __restrict__ alpha_mod, const float* __restrict__ omega_mod,
    const __bf16* __restrict__ Uarr, const float* __restrict__ dt,
    const float* __restrict__ tau_mod, const float* __restrict__ s_real,
    const float* __restrict__ s_imag, const float* __restrict__ tau_raw,
    const float* __restrict__ bvec,
    float2* __restrict__ sumA, float2* __restrict__ sumT,
    float2* __restrict__ Zr, float2* __restrict__ Zi){
  const int t = threadIdx.x;
  const int kh = t & 63;        // k-pair index: k = kh*2, kh*2+1
  const int cl = t >> 6;        // chunk-local 0..3
  const int b = blockIdx.y;
  const int c = blockIdx.x*4 + cl;
  const int t0 = c * TC;
  __shared__ float sdt[4*TC], ssc[4*TC];
  if (t < 4*TC){
    const int tg = blockIdx.x*4*TC + t;
    sdt[t] = dt[b*T_SZ + tg];
    ssc[t] = __expf(tau_mod[b*T_SZ + tg]);
  }
  __syncthreads();
  const float tau = softplus_f(tau_raw[0]) + 1e-3f;
  const float2 sr = ((const float2*)s_real)[kh];
  const float2 si = ((const float2*)s_imag)[kh];
  const float2 bk = ((const float2*)bvec)[kh];
  const float a0[2] = {(softplus_f(sr.x)+1e-6f)*tau, (softplus_f(sr.y)+1e-6f)*tau};
  const float w0[2] = {si.x*tau, si.y*tau};
  float zr[2]={0,0}, zs[2]={0,0}, sA[2]={0,0}, sT[2]={0,0};
  const float* sd = sdt + cl*TC;
  const float* ss = ssc + cl*TC;
  const size_t row = (size_t)(b*T_SZ + t0);
  const float2* amp = (const float2*)(alpha_mod + row*K_SZ) + kh;
  const float2* omp = (const float2*)(omega_mod + row*K_SZ) + kh;
  const bf16x2* up  = (const bf16x2*)(Uarr + row*K_SZ) + kh;
  #pragma unroll 8
  for (int i = 0; i < TC; ++i){
    const float2 am = amp[(size_t)i*64];
    const float2 om = omp[(size_t)i*64];
    const bf16x2 u2 = up[(size_t)i*64];
    const float scdt = ss[i] * sd[i];
    #pragma unroll
    for (int j = 0; j < 2; ++j){
      const float ad = a0[j] * __expf(j ? am.y : am.x) * scdt;
      const float th = w0[j] * __expf(j ? om.y : om.x) * scdt;
      const float rho = __expf(-ad);
      float st, ct; __sincosf(th, &st, &ct);
      const float uu = (float)u2[j] + (j ? bk.y : bk.x);
      const float nr = rho*(zr[j]*ct - zs[j]*st) + uu;
      const float ns = rho*(zr[j]*st + zs[j]*ct);
      zr[j] = nr; zs[j] = ns;
      sA[j] += ad; sT[j] += th;
    }
  }
  const size_t idx = ((size_t)(b*NC + c))*64 + kh;
  sumA[idx] = make_float2(sA[0], sA[1]);
  sumT[idx] = make_float2(sT[0], sT[1]);
  Zr[idx]   = make_float2(zr[0], zr[1]);
  Zi[idx]   = make_float2(zs[0], zs[1]);
}

// ---------------------------------------------------------------------------
// Kernel 4 (pass B): wave-parallel Kogge-Stone scan of the chunk summaries.
// One wave per (b, channel): 32*128 = 4096 waves. Lane l owns chunks 2l,2l+1:
// compose the pair serially, scan the 64 lane-composites in 6 shuffle steps
// (affine complex compose), then exclusive-prefix fixup. Depth 128 -> 8.
// ---------------------------------------------------------------------------
__global__ __launch_bounds__(256) void pass_b(
    const float* __restrict__ sumA, const float* __restrict__ sumT,
    const float* __restrict__ Zr, const float* __restrict__ Zi,
    float* __restrict__ Cr, float* __restrict__ Ci){
  const int gwave = (blockIdx.x*256 + threadIdx.x) >> 6;  // 0..4095
  const int lane  = threadIdx.x & 63;
  const int b  = gwave >> 7;         // 128 channels per batch
  const int ch = gwave & 127;        // channel = kh*2 + j
  // float index of chunk c's element for this channel: (b*NC + c)*128 + ch
  const size_t i0 = ((size_t)(b*NC) + lane*2)*128 + ch;
  const size_t i1 = i0 + 128;
  const float sa0 = sumA[i0], sa1 = sumA[i1];
  const float th0 = sumT[i0], th1 = sumT[i1];
  const float ur0 = Zr[i0],   ur1 = Zr[i1];
  const float ui0 = Zi[i0],   ui1 = Zi[i1];
  const float r0 = __expf(-sa0), r1 = __expf(-sa1);
  float s0, cc0, s1, cc1;
  __sincosf(th0, &s0, &cc0); __sincosf(th1, &s1, &cc1);
  const float a0r = r0*cc0, a0i = r0*s0;
  const float a1r = r1*cc1, a1i = r1*s1;
  // lane composite F = f1 ∘ f0 : a = a1*a0, u = a1*u0 + u1
  float Fr = a1r*a0r - a1i*a0i;
  float Fi = a1r*a0i + a1i*a0r;
  float Ur = a1r*ur0 - a1i*ui0 + ur1;
  float Ui = a1r*ui0 + a1i*ur0 + ui1;
  // Kogge-Stone inclusive scan (compose self ∘ prev)
  #pragma unroll
  for (int d = 1; d < 64; d <<= 1){
    const float pFr = __shfl_up(Fr, d, 64);
    const float pFi = __shfl_up(Fi, d, 64);
    const float pUr = __shfl_up(Ur, d, 64);
    const float pUi = __shfl_up(Ui, d, 64);
    if (lane >= d){
      const float nFr = Fr*pFr - Fi*pFi;
      const float nFi = Fr*pFi + Fi*pFr;
      const float nUr = Fr*pUr - Fi*pUi + Ur;
      const float nUi = Fr*pUi + Fi*pUr + Ui;
      Fr = nFr; Fi = nFi; Ur = nUr; Ui = nUi;
    }
  }
  // exclusive prefix for chunk 2l = inclusive U of lane l-1 (0 for lane 0)
  float e0r = __shfl_up(Ur, 1, 64);
  float e0i = __shfl_up(Ui, 1, 64);
  if (lane == 0){ e0r = 0.f; e0i = 0.f; }
  // exclusive for chunk 2l+1 = f_{2l}(e0)
  const float e1r = a0r*e0r - a0i*e0i + ur0;
  const float e1i = a0r*e0i + a0i*e0r + ui0;
  Cr[i0] = e0r; Ci[i0] = e0i;
  Cr[i1] = e1r; Ci[i1] = e1i;
}

// ---------------------------------------------------------------------------
// Kernel 5 (pass C): replay chunks from carry-in, write [B,T,2K] output
// ---------------------------------------------------------------------------
__global__ __launch_bounds__(256) void pass_c(
    const float* __restrict__ alpha_mod, const float* __restrict__ omega_mod,
    const __bf16* __restrict__ Uarr, const float* __restrict__ dt,
    const float* __restrict__ tau_mod, const float* __restrict__ s_real,
    const float* __restrict__ s_imag, const float* __restrict__ tau_raw,
    const float* __restrict__ bvec,
    const float2* __restrict__ Cr, const float2* __restrict__ Ci,
    float* __restrict__ out){
  const int t = threadIdx.x;
  const int kh = t & 63;
  const int cl = t >> 6;
  const int b = blockIdx.y;
  const int c = blockIdx.x*4 + cl;
  const int t0 = c * TC;
  __shared__ float sdt[4*TC], ssc[4*TC];
  if (t < 4*TC){
    const int tg = blockIdx.x*4*TC + t;
    sdt[t] = dt[b*T_SZ + tg];
    ssc[t] = __expf(tau_mod[b*T_SZ + tg]);
  }
  __syncthreads();
  const float tau = softplus_f(tau_raw[0]) + 1e-3f;
  const float2 sr = ((const float2*)s_real)[kh];
  const float2 si = ((const float2*)s_imag)[kh];
  const float2 bk = ((const float2*)bvec)[kh];
  const float a0[2] = {(softplus_f(sr.x)+1e-6f)*tau, (softplus_f(sr.y)+1e-6f)*tau};
  const float w0[2] = {si.x*tau, si.y*tau};
  const size_t cidx = ((size_t)(b*NC + c))*64 + kh;
  const float2 cr = Cr[cidx], cim = Ci[cidx];
  float zr[2] = {cr.x, cr.y}, zs[2] = {cim.x, cim.y};
  const float* sd = sdt + cl*TC;
  const float* ss = ssc + cl*TC;
  const size_t row = (size_t)(b*T_SZ + t0);
  const float2* amp = (const float2*)(alpha_mod + row*K_SZ) + kh;
  const float2* omp = (const float2*)(omega_mod + row*K_SZ) + kh;
  const bf16x2* up  = (const bf16x2*)(Uarr + row*K_SZ) + kh;
  float2* outC = (float2*)(out + row*(2*K_SZ)) + kh;          // stride 128 float2 per t
  float2* outS = outC + 64;
  #pragma unroll 8
  for (int i = 0; i < TC; ++i){
    const float2 am = amp[(size_t)i*64];
    const float2 om = omp[(size_t)i*64];
    const bf16x2 u2 = up[(size_t)i*64];
    const float scdt = ss[i] * sd[i];
    #pragma unroll
    for (int j = 0; j < 2; ++j){
      const float ad = a0[j] * __expf(j ? am.y : am.x) * scdt;
      const float th = w0[j] * __expf(j ? om.y : om.x) * scdt;
      const float rho = __expf(-ad);
      float st, ct; __sincosf(th, &st, &ct);
      const float uu = (float)u2[j] + (j ? bk.y : bk.x);
      const float nr = rho*(zr[j]*ct - zs[j]*st) + uu;
      const float ns = rho*(zr[j]*st + zs[j]*ct);
      zr[j] = nr; zs[j] = ns;
    }
    outC[(size_t)i*128] = make_float2(zr[0], zr[1]);
    outS[(size_t)i*128] = make_float2(zs[0], zs[1]);
  }
}

// ---------------------------------------------------------------------------
extern "C" void kernel_launch(void* const* d_in, const int* in_sizes, int n_in,
                              void* d_out, int out_size, void* d_ws, size_t ws_size,
                              hipStream_t stream){
  (void)in_sizes; (void)n_in; (void)out_size; (void)ws_size;
  const float* x         = (const float*)d_in[0];
  const float* dt        = (const float*)d_in[1];
  const float* alpha_mod = (const float*)d_in[2];
  const float* omega_mod = (const float*)d_in[3];
  const float* tau_mod   = (const float*)d_in[4];
  const float* s_real    = (const float*)d_in[5];
  const float* s_imag    = (const float*)d_in[6];
  const float* tau_raw   = (const float*)d_in[7];
  const float* W         = (const float*)d_in[8];
  const float* bvec      = (const float*)d_in[9];
  const float* u_sn      = (const float*)d_in[10];
  float* out = (float*)d_out;

  char* w = (char*)d_ws;
  __bf16* Wb = (__bf16*)w;                                  // 128 KiB (frag-ordered)
  __bf16* U  = (__bf16*)(w + 131072);                       // 16 MiB (bf16 u)
  size_t off = 131072 + (size_t)B_SZ*T_SZ*K_SZ*2;
  const size_t SUMN = (size_t)B_SZ*NC*K_SZ*4;               // 2 MiB each
  float2* sumA = (float2*)(w + off); off += SUMN;
  float2* sumT = (float2*)(w + off); off += SUMN;
  float2* Zr   = (float2*)(w + off); off += SUMN;
  float2* Zi   = (float2*)(w + off); off += SUMN;
  float2* Cr   = (float2*)(w + off); off += SUMN;
  float2* Ci   = (float2*)(w + off); off += SUMN;

  sn_prep<<<1, 512, 0, stream>>>(W, u_sn, Wb);
  gemm_xw<<<(B_SZ*T_SZ)/128, 256, 0, stream>>>(x, Wb, U);
  pass_a<<<dim3(NC/4, B_SZ), 256, 0, stream>>>(alpha_mod, omega_mod, U, dt, tau_mod,
                                               s_real, s_imag, tau_raw, bvec,
                                               sumA, sumT, Zr, Zi);
  pass_b<<<(B_SZ*K_SZ)/4, 256, 0, stream>>>((const float*)sumA, (const float*)sumT,
                                            (const float*)Zr, (const float*)Zi,
                                            (float*)Cr, (float*)Ci);
  pass_c<<<dim3(NC/4, B_SZ), 256, 0, stream>>>(alpha_mod, omega_mod, U, dt, tau_mod,
                                               s_real, s_imag, tau_raw, bvec,
                                               Cr, Ci, out);
}

// Round 3
// 327.736 us; speedup vs baseline: 1.2822x; 1.0862x over previous
//
#include <hip/hip_runtime.h>
#include <hip/hip_bf16.h>
#include <math.h>

typedef __bf16 bf16x8 __attribute__((ext_vector_type(8)));
typedef __bf16 bf16x4 __attribute__((ext_vector_type(4)));
typedef __bf16 bf16x2 __attribute__((ext_vector_type(2)));
typedef float f32x4 __attribute__((ext_vector_type(4)));

#define B_SZ 32
#define T_SZ 2048
#define D_SZ 512
#define K_SZ 128
#define TC 32
#define NC 64   // T_SZ / TC

__device__ __forceinline__ float softplus_f(float x){
  return x > 20.f ? x : log1pf(expf(x));
}

// ---------------------------------------------------------------------------
// Kernel 1a: spectral norm power iteration -> writes 1/sigma to workspace.
// Single block (global reductions), no W rewrite here.
// ---------------------------------------------------------------------------
__global__ __launch_bounds__(512) void sn_pi(const float* __restrict__ W,
                                             const float* __restrict__ u_sn,
                                             float* __restrict__ sig_inv){
  __shared__ float red[512];
  __shared__ float vsh[512];
  __shared__ float ush[128];
  const int t = threadIdx.x;
  if (t < 128) ush[t] = u_sn[t];
  __syncthreads();
  // t1[d] = sum_k W[k,d] * u[k]   (coalesced over d)
  float t1 = 0.f;
  #pragma unroll 8
  for (int k = 0; k < K_SZ; ++k) t1 += W[k*D_SZ + t] * ush[k];
  red[t] = t1 * t1;
  __syncthreads();
  for (int s = 256; s > 0; s >>= 1){ if (t < s) red[t] += red[t+s]; __syncthreads(); }
  const float n1 = sqrtf(red[0]);
  vsh[t] = t1 / (n1 + 1e-6f);
  __syncthreads();
  // t2[k] = sum_d W[k,d] * v[d]  (float4 per row)
  float t2 = 0.f;
  if (t < 128){
    const float4* Wr = (const float4*)(W + (size_t)t * D_SZ);
    const float4* vp = (const float4*)vsh;
    #pragma unroll 8
    for (int d = 0; d < D_SZ/4; ++d){
      const float4 a = Wr[d], v = vp[d];
      t2 += a.x*v.x + a.y*v.y + a.z*v.z + a.w*v.w;
    }
  }
  __syncthreads();
  red[t] = (t < 128) ? t2*t2 : 0.f;
  __syncthreads();
  for (int s = 256; s > 0; s >>= 1){ if (t < s) red[t] += red[t+s]; __syncthreads(); }
  if (t == 0){
    const float n2sq = red[0];
    const float sigma = n2sq / (sqrtf(n2sq) + 1e-6f);   // u1 . (W v)
    sig_inv[0] = 1.f / sigma;
  }
}

// ---------------------------------------------------------------------------
// Kernel 1b: scale W by 1/sigma into bf16, row-major. 64 blocks x 256 thr,
// one float4 -> bf16x4 per thread (was serial inside the single-block sn_prep).
// ---------------------------------------------------------------------------
__global__ __launch_bounds__(256) void sn_scale(const float* __restrict__ W,
                                                const float* __restrict__ sig_inv,
                                                __bf16* __restrict__ Wb){
  const float inv = sig_inv[0];
  const int i = blockIdx.x*256 + threadIdx.x;   // 0..16383
  const float4 v = ((const float4*)W)[i];
  bf16x4 o; o[0]=(__bf16)(v.x*inv); o[1]=(__bf16)(v.y*inv);
  o[2]=(__bf16)(v.z*inv); o[3]=(__bf16)(v.w*inv);
  ((bf16x4*)Wb)[i] = o;
}

// ---------------------------------------------------------------------------
// Kernel 2: u = x @ W_sn^T   (M=65536, N=128, K=512), bf16 MFMA, bf16 out.
// Double-buffered LDS, one barrier per K-iter, register prefetch of the next
// tile issued right after the barrier so loads complete under MFMA.
// LDS chunks XOR-swizzled: phys = (fb*64+ll) ^ cg -> conflict-free writes
// ((row&7)^cg spans all 8 bank groups) AND conflict-free reads.
// (exact round-0 version — harness-proven at 334 us total)
// ---------------------------------------------------------------------------
__global__ __launch_bounds__(256) void gemm_xw(const float* __restrict__ X,
                                               const __bf16* __restrict__ Wb,
                                               __bf16* __restrict__ U){
  __shared__ bf16x8 As[2][1024];   // 32 KB
  __shared__ bf16x8 Bs[2][1024];   // 32 KB
  const int tid = threadIdx.x;
  const int lane = tid & 63;
  const int wid = tid >> 6;
  const int wm = wid >> 1, wn = wid & 1;
  const int rowbase = blockIdx.x * 128;
  const int L15 = lane & 15, Lq = lane >> 4;
  f32x4 acc[4][4] = {};

  // staging coordinates: thread covers rows rowA+32r, col group cg (8 cols)
  const int rowA = tid >> 3;      // 0..31
  const int cg   = tid & 7;
  const int colo = cg * 8;
  int pidx[4];
  #pragma unroll
  for (int r = 0; r < 4; ++r){
    const int row = rowA + 32*r;
    const int fb = ((row >> 4) << 1) | (cg >> 2);
    const int ll = (row & 15) | ((cg & 3) << 4);
    pidx[r] = (fb*64 + ll) ^ cg;
  }
  const float* Xb  = X  + (size_t)(rowbase + rowA)*D_SZ + colo;
  const __bf16* Bb = Wb + (size_t)rowA*D_SZ + colo;

  float4 va[4], vb[4];
  bf16x8 wreg[4];
  #pragma unroll
  for (int r = 0; r < 4; ++r){
    const float4* q = (const float4*)(Xb + (size_t)(32*r)*D_SZ);
    va[r] = q[0]; vb[r] = q[1];
    wreg[r] = *(const bf16x8*)(Bb + (size_t)(32*r)*D_SZ);
  }

  int pb = 0;
  for (int kk = 0; kk < D_SZ; kk += 64){
    #pragma unroll
    for (int r = 0; r < 4; ++r){
      bf16x8 f;
      f[0]=(__bf16)va[r].x; f[1]=(__bf16)va[r].y; f[2]=(__bf16)va[r].z; f[3]=(__bf16)va[r].w;
      f[4]=(__bf16)vb[r].x; f[5]=(__bf16)vb[r].y; f[6]=(__bf16)vb[r].z; f[7]=(__bf16)vb[r].w;
      As[pb][pidx[r]] = f;
      Bs[pb][pidx[r]] = wreg[r];
    }
    __syncthreads();
    if (kk + 64 < D_SZ){
      #pragma unroll
      for (int r = 0; r < 4; ++r){
        const float4* q = (const float4*)(Xb + (size_t)(32*r)*D_SZ + kk + 64);
        va[r] = q[0]; vb[r] = q[1];
        wreg[r] = *(const bf16x8*)(Bb + (size_t)(32*r)*D_SZ + kk + 64);
      }
    }
    #pragma unroll
    for (int s = 0; s < 2; ++s){
      bf16x8 af[4], bfr[4];
      const int swz = (s << 2) | (lane >> 4);
      #pragma unroll
      for (int ii = 0; ii < 4; ++ii){
        const int fb = ((wm*4+ii) << 1) | s;
        af[ii] = As[pb][(fb*64 + lane) ^ swz];
      }
      #pragma unroll
      for (int jj = 0; jj < 4; ++jj){
        const int fb = ((wn*4+jj) << 1) | s;
        bfr[jj] = Bs[pb][(fb*64 + lane) ^ swz];
      }
      #pragma unroll
      for (int ii = 0; ii < 4; ++ii)
        #pragma unroll
        for (int jj = 0; jj < 4; ++jj)
          acc[ii][jj] = __builtin_amdgcn_mfma_f32_16x16x32_bf16(af[ii], bfr[jj], acc[ii][jj], 0, 0, 0);
    }
    pb ^= 1;
  }
  // epilogue: C/D layout col = lane&15, row = (lane>>4)*4 + reg (m89-verified)
  #pragma unroll
  for (int ii = 0; ii < 4; ++ii){
    const int m = rowbase + (wm*4+ii)*16 + (Lq << 2);
    #pragma unroll
    for (int jj = 0; jj < 4; ++jj){
      const int n = (wn*4+jj)*16 + L15;
      #pragma unroll
      for (int r = 0; r < 4; ++r)
        U[(size_t)(m + r)*K_SZ + n] = (__bf16)acc[ii][jj][r];
    }
  }
}

// ---------------------------------------------------------------------------
// Kernel 3 (pass A): per-chunk summaries. Thread = (chunk, 2 k-channels).
// Block = 256 threads = 4 chunks x 64 k-pairs. Grid = (NC/4, B).
// (exact round-0 version)
// ---------------------------------------------------------------------------
__global__ __launch_bounds__(256) void pass_a(
    const float* __restrict__ alpha_mod, const float* __restrict__ omega_mod,
    const __bf16* __restrict__ Uarr, const float* __restrict__ dt,
    const float* __restrict__ tau_mod, const float* __restrict__ s_real,
    const float* __restrict__ s_imag, const float* __restrict__ tau_raw,
    const float* __restrict__ bvec,
    float2* __restrict__ sumA, float2* __restrict__ sumT,
    float2* __restrict__ Zr, float2* __restrict__ Zi){
  const int t = threadIdx.x;
  const int kh = t & 63;        // k-pair index: k = kh*2, kh*2+1
  const int cl = t >> 6;        // chunk-local 0..3
  const int b = blockIdx.y;
  const int c = blockIdx.x*4 + cl;
  const int t0 = c * TC;
  __shared__ float sdt[4*TC], ssc[4*TC];
  if (t < 4*TC){
    const int tg = blockIdx.x*4*TC + t;
    sdt[t] = dt[b*T_SZ + tg];
    ssc[t] = __expf(tau_mod[b*T_SZ + tg]);
  }
  __syncthreads();
  const float tau = softplus_f(tau_raw[0]) + 1e-3f;
  const float2 sr = ((const float2*)s_real)[kh];
  const float2 si = ((const float2*)s_imag)[kh];
  const float2 bk = ((const float2*)bvec)[kh];
  const float a0[2] = {(softplus_f(sr.x)+1e-6f)*tau, (softplus_f(sr.y)+1e-6f)*tau};
  const float w0[2] = {si.x*tau, si.y*tau};
  float zr[2]={0,0}, zs[2]={0,0}, sA[2]={0,0}, sT[2]={0,0};
  const float* sd = sdt + cl*TC;
  const float* ss = ssc + cl*TC;
  const size_t row = (size_t)(b*T_SZ + t0);
  const float2* amp = (const float2*)(alpha_mod + row*K_SZ) + kh;
  const float2* omp = (const float2*)(omega_mod + row*K_SZ) + kh;
  const bf16x2* up  = (const bf16x2*)(Uarr + row*K_SZ) + kh;
  #pragma unroll 4
  for (int i = 0; i < TC; ++i){
    const float2 am = amp[(size_t)i*64];
    const float2 om = omp[(size_t)i*64];
    const bf16x2 u2 = up[(size_t)i*64];
    const float scdt = ss[i] * sd[i];
    #pragma unroll
    for (int j = 0; j < 2; ++j){
      const float ad = a0[j] * __expf(j ? am.y : am.x) * scdt;
      const float th = w0[j] * __expf(j ? om.y : om.x) * scdt;
      const float rho = __expf(-ad);
      float st, ct; __sincosf(th, &st, &ct);
      const float uu = (float)u2[j] + (j ? bk.y : bk.x);
      const float nr = rho*(zr[j]*ct - zs[j]*st) + uu;
      const float ns = rho*(zr[j]*st + zs[j]*ct);
      zr[j] = nr; zs[j] = ns;
      sA[j] += ad; sT[j] += th;
    }
  }
  const size_t idx = ((size_t)(b*NC + c))*64 + kh;
  sumA[idx] = make_float2(sA[0], sA[1]);
  sumT[idx] = make_float2(sT[0], sT[1]);
  Zr[idx]   = make_float2(zr[0], zr[1]);
  Zi[idx]   = make_float2(zs[0], zs[1]);
}

// ---------------------------------------------------------------------------
// Kernel 4 (pass B): wave-parallel Kogge-Stone scan of the chunk summaries.
// One wave per (b, channel): 32*128 = 4096 waves. Lane l owns chunk l
// (NC=64 = wave width), scan the 64 affine complex maps in 6 shuffle steps,
// exclusive prefix via shfl_up(1). Depth 64 -> 7.
// ---------------------------------------------------------------------------
__global__ __launch_bounds__(256) void pass_b(
    const float* __restrict__ sumA, const float* __restrict__ sumT,
    const float* __restrict__ Zr, const float* __restrict__ Zi,
    float* __restrict__ Cr, float* __restrict__ Ci){
  const int gwave = (blockIdx.x*256 + threadIdx.x) >> 6;  // 0..4095
  const int lane  = threadIdx.x & 63;
  const int b  = gwave >> 7;         // 128 channels per batch
  const int ch = gwave & 127;        // channel = kh*2 + j
  // float index of chunk c=lane's element for this channel
  const size_t i0 = ((size_t)(b*NC) + lane)*128 + ch;
  const float sa = sumA[i0], th = sumT[i0];
  const float r = __expf(-sa);
  float s, c; __sincosf(th, &s, &c);
  float Fr = r*c, Fi = r*s;
  float Ur = Zr[i0], Ui = Zi[i0];
  // Kogge-Stone inclusive scan (compose self ∘ prev)
  #pragma unroll
  for (int d = 1; d < 64; d <<= 1){
    const float pFr = __shfl_up(Fr, d, 64);
    const float pFi = __shfl_up(Fi, d, 64);
    const float pUr = __shfl_up(Ur, d, 64);
    const float pUi = __shfl_up(Ui, d, 64);
    if (lane >= d){
      const float nFr = Fr*pFr - Fi*pFi;
      const float nFi = Fr*pFi + Fi*pFr;
      const float nUr = Fr*pUr - Fi*pUi + Ur;
      const float nUi = Fr*pUi + Fi*pUr + Ui;
      Fr = nFr; Fi = nFi; Ur = nUr; Ui = nUi;
    }
  }
  // exclusive prefix for chunk l = inclusive U of lane l-1 (0 for lane 0)
  float er = __shfl_up(Ur, 1, 64);
  float ei = __shfl_up(Ui, 1, 64);
  if (lane == 0){ er = 0.f; ei = 0.f; }
  Cr[i0] = er; Ci[i0] = ei;
}

// ---------------------------------------------------------------------------
// Kernel 5 (pass C): replay chunks from carry-in, write [B,T,2K] output
// (exact round-0 version)
// ---------------------------------------------------------------------------
__global__ __launch_bounds__(256) void pass_c(
    const float* __restrict__ alpha_mod, const float* __restrict__ omega_mod,
    const __bf16* __restrict__ Uarr, const float* __restrict__ dt,
    const float* __restrict__ tau_mod, const float* __restrict__ s_real,
    const float* __restrict__ s_imag, const float* __restrict__ tau_raw,
    const float* __restrict__ bvec,
    const float2* __restrict__ Cr, const float2* __restrict__ Ci,
    float* __restrict__ out){
  const int t = threadIdx.x;
  const int kh = t & 63;
  const int cl = t >> 6;
  const int b = blockIdx.y;
  const int c = blockIdx.x*4 + cl;
  const int t0 = c * TC;
  __shared__ float sdt[4*TC], ssc[4*TC];
  if (t < 4*TC){
    const int tg = blockIdx.x*4*TC + t;
    sdt[t] = dt[b*T_SZ + tg];
    ssc[t] = __expf(tau_mod[b*T_SZ + tg]);
  }
  __syncthreads();
  const float tau = softplus_f(tau_raw[0]) + 1e-3f;
  const float2 sr = ((const float2*)s_real)[kh];
  const float2 si = ((const float2*)s_imag)[kh];
  const float2 bk = ((const float2*)bvec)[kh];
  const float a0[2] = {(softplus_f(sr.x)+1e-6f)*tau, (softplus_f(sr.y)+1e-6f)*tau};
  const float w0[2] = {si.x*tau, si.y*tau};
  const size_t cidx = ((size_t)(b*NC + c))*64 + kh;
  const float2 cr = Cr[cidx], cim = Ci[cidx];
  float zr[2] = {cr.x, cr.y}, zs[2] = {cim.x, cim.y};
  const float* sd = sdt + cl*TC;
  const float* ss = ssc + cl*TC;
  const size_t row = (size_t)(b*T_SZ + t0);
  const float2* amp = (const float2*)(alpha_mod + row*K_SZ) + kh;
  const float2* omp = (const float2*)(omega_mod + row*K_SZ) + kh;
  const bf16x2* up  = (const bf16x2*)(Uarr + row*K_SZ) + kh;
  float2* outC = (float2*)(out + row*(2*K_SZ)) + kh;          // stride 128 float2 per t
  float2* outS = outC + 64;
  #pragma unroll 4
  for (int i = 0; i < TC; ++i){
    const float2 am = amp[(size_t)i*64];
    const float2 om = omp[(size_t)i*64];
    const bf16x2 u2 = up[(size_t)i*64];
    const float scdt = ss[i] * sd[i];
    #pragma unroll
    for (int j = 0; j < 2; ++j){
      const float ad = a0[j] * __expf(j ? am.y : am.x) * scdt;
      const float th = w0[j] * __expf(j ? om.y : om.x) * scdt;
      const float rho = __expf(-ad);
      float st, ct; __sincosf(th, &st, &ct);
      const float uu = (float)u2[j] + (j ? bk.y : bk.x);
      const float nr = rho*(zr[j]*ct - zs[j]*st) + uu;
      const float ns = rho*(zr[j]*st + zs[j]*ct);
      zr[j] = nr; zs[j] = ns;
    }
    outC[(size_t)i*128] = make_float2(zr[0], zr[1]);
    outS[(size_t)i*128] = make_float2(zs[0], zs[1]);
  }
}

// ---------------------------------------------------------------------------
extern "C" void kernel_launch(void* const* d_in, const int* in_sizes, int n_in,
                              void* d_out, int out_size, void* d_ws, size_t ws_size,
                              hipStream_t stream){
  (void)in_sizes; (void)n_in; (void)out_size; (void)ws_size;
  const float* x         = (const float*)d_in[0];
  const float* dt        = (const float*)d_in[1];
  const float* alpha_mod = (const float*)d_in[2];
  const float* omega_mod = (const float*)d_in[3];
  const float* tau_mod   = (const float*)d_in[4];
  const float* s_real    = (const float*)d_in[5];
  const float* s_imag    = (const float*)d_in[6];
  const float* tau_raw   = (const float*)d_in[7];
  const float* W         = (const float*)d_in[8];
  const float* bvec      = (const float*)d_in[9];
  const float* u_sn      = (const float*)d_in[10];
  float* out = (float*)d_out;

  char* w = (char*)d_ws;
  __bf16* Wb = (__bf16*)w;                                  // 128 KiB
  __bf16* U  = (__bf16*)(w + 131072);                       // 16 MiB (bf16 u)
  size_t off = 131072 + (size_t)B_SZ*T_SZ*K_SZ*2;
  const size_t SUMN = (size_t)B_SZ*NC*K_SZ*4;               // 1 MiB each
  float2* sumA = (float2*)(w + off); off += SUMN;
  float2* sumT = (float2*)(w + off); off += SUMN;
  float2* Zr   = (float2*)(w + off); off += SUMN;
  float2* Zi   = (float2*)(w + off); off += SUMN;
  float2* Cr   = (float2*)(w + off); off += SUMN;
  float2* Ci   = (float2*)(w + off); off += SUMN;
  float* sig   = (float*)(w + off);  off += 256;

  sn_pi<<<1, 512, 0, stream>>>(W, u_sn, sig);
  sn_scale<<<64, 256, 0, stream>>>(W, sig, Wb);
  gemm_xw<<<(B_SZ*T_SZ)/128, 256, 0, stream>>>(x, Wb, U);
  pass_a<<<dim3(NC/4, B_SZ), 256, 0, stream>>>(alpha_mod, omega_mod, U, dt, tau_mod,
                                               s_real, s_imag, tau_raw, bvec,
                                               sumA, sumT, Zr, Zi);
  pass_b<<<(B_SZ*K_SZ)/4, 256, 0, stream>>>((const float*)sumA, (const float*)sumT,
                                            (const float*)Zr, (const float*)Zi,
                                            (float*)Cr, (float*)Ci);
  pass_c<<<dim3(NC/4, B_SZ), 256, 0, stream>>>(alpha_mod, omega_mod, U, dt, tau_mod,
                                               s_real, s_imag, tau_raw, bvec,
                                               Cr, Ci, out);
}